// Round 5
// baseline (287.691 us; speedup 1.0000x reference)
//
#include <hip/hip_runtime.h>

// Resample2d: backward warp of input1 (B,C,H,W) by flow input2 (B,2,H,W).
// Bilinear, border padding (clamp). B=8 C=64 H=256 W=448, all fp32.
//
// Round 5: the gathers' per-lane-random y0 splits each wave load into
// ~16+ cache-line transactions (TA-throughput bound, ~95us floor).
// Fix: stage NS=24 image rows in LDS per (block,channel) and gather via
// ds_read (scatter-immune, ~5.8cyc/instr; banks = x0%32, conflict-light).
// Block = 448 thr (one column each) x 8 output rows x 8 channels.
// T14 async-split prefetch of next channel across a raw s_barrier with
// lgkmcnt-only wait. Rare |fy|>~8 outliers fall back to global loads.

#define RB 8
#define RC 64
#define RH 256
#define RW 448
#define RHW (RH * RW)
#define TPB 448                    // 7 waves
#define ROWS 8                     // output rows per block
#define NS 24                      // staged rows (ROWS + 16 margin)
#define CS 8                       // channel groups
#define CPB (RC / CS)              // 8 channels per block
#define YT (RH / ROWS)             // 32 y-tiles
#define NBLK (RB * CS * YT)        // 2048 blocks
#define NXCD 8
#define STAGE_F4 (NS * RW / 4)     // 2688 float4 per channel
#define F4T (STAGE_F4 / TPB)       // 6 float4 per thread (exact)

__global__ __launch_bounds__(TPB) void resample2d_kernel(
    const float* __restrict__ img,   // (B,C,H,W)
    const float* __restrict__ flow,  // (B,2,H,W)
    float* __restrict__ out)         // (B,C,H,W)
{
    __shared__ float sm[NS * RW];    // 43008 B

    // Bijective XCD-chunked swizzle (NBLK % 8 == 0): consecutive ids sweep
    // y-tiles of one (b,cgroup) -> staging halo rows hit the same XCD L2.
    int bid = blockIdx.x;
    const int chunk = NBLK / NXCD;               // 256
    int id = (bid & (NXCD - 1)) * chunk + (bid >> 3);

    int b  = id / (CS * YT);
    int rm = id % (CS * YT);
    int cg = rm / YT;
    int ybase = (rm % YT) * ROWS;
    int ys0 = min(max(ybase - 8, 0), RH - NS);   // staged window start row

    int tid = threadIdx.x;                        // == x column (0..447)

    // Per-pixel clamped sample coords (channel-invariant): 16 VGPRs.
    float xf[ROWS], yf[ROWS];
    const float* flb = flow + (size_t)b * 2 * RHW;
    #pragma unroll
    for (int r = 0; r < ROWS; ++r) {
        int y = ybase + r;
        float fx = flb[(size_t)y * RW + tid];
        float fy = flb[RHW + (size_t)y * RW + tid];
        xf[r] = fminf(fmaxf((float)tid + fx, 0.0f), (float)(RW - 1));
        yf[r] = fminf(fmaxf((float)y   + fy, 0.0f), (float)(RH - 1));
    }

    const float* imgg = img + ((size_t)b * RC + (size_t)cg * CPB) * RHW;
    float* outg       = out + ((size_t)b * RC + (size_t)cg * CPB) * RHW;

    // Prologue: prefetch channel 0's staged rows into registers.
    float4 pf[F4T];
    {
        const float4* s0 = (const float4*)(imgg + (size_t)ys0 * RW);
        #pragma unroll
        for (int k = 0; k < F4T; ++k) pf[k] = s0[tid + k * TPB];
    }

    for (int c = 0; c < CPB; ++c) {
        // Write staged channel c into LDS.
        float4* smf4 = (float4*)sm;
        #pragma unroll
        for (int k = 0; k < F4T; ++k) smf4[tid + k * TPB] = pf[k];

        // Prefetch channel c+1 (stays in flight across the raw barrier).
        if (c + 1 < CPB) {
            const float4* sn =
                (const float4*)(imgg + (size_t)(c + 1) * RHW + (size_t)ys0 * RW);
            #pragma unroll
            for (int k = 0; k < F4T; ++k) pf[k] = sn[tid + k * TPB];
        }

        // Barrier: wait only LDS writes; leave the global prefetch in flight.
        asm volatile("s_waitcnt lgkmcnt(0)" ::: "memory");
        __builtin_amdgcn_s_barrier();

        const float* p = imgg + (size_t)c * RHW;   // fallback plane
        float* q       = outg + (size_t)c * RHW;

        #pragma unroll
        for (int r = 0; r < ROWS; ++r) {
            float xr = xf[r], yr = yf[r];
            float x0f = floorf(xr), y0f = floorf(yr);
            float wx = xr - x0f,   wy = yr - y0f;
            int x0 = (int)x0f,     y0 = (int)y0f;
            int x1 = min(x0 + 1, RW - 1);
            int y1 = min(y0 + 1, RH - 1);
            int dx = x1 - x0;                       // 0 or 1
            int ly0 = y0 - ys0, ly1 = y1 - ys0;

            float v00, v01, v10, v11;
            if (((unsigned)ly0 < NS) & ((unsigned)ly1 < NS)) {
                int o00 = ly0 * RW + x0;
                int o10 = ly1 * RW + x0;
                v00 = sm[o00];       v01 = sm[o00 + dx];
                v10 = sm[o10];       v11 = sm[o10 + dx];
            } else {                                 // rare outlier fallback
                int g00 = y0 * RW + x0;
                int g10 = y1 * RW + x0;
                v00 = p[g00];        v01 = p[g00 + dx];
                v10 = p[g10];        v11 = p[g10 + dx];
            }

            float w00 = (1.0f - wx) * (1.0f - wy);
            float w01 = wx * (1.0f - wy);
            float w10 = (1.0f - wx) * wy;
            float w11 = wx * wy;
            float v = v00 * w00 + v01 * w01 + v10 * w10 + v11 * w11;
            __builtin_nontemporal_store(v, q + (size_t)(ybase + r) * RW + tid);
        }

        // Barrier before next channel's LDS overwrite: wait this wave's
        // ds_reads (lgkm) only; global stores/prefetch keep flowing.
        asm volatile("s_waitcnt lgkmcnt(0)" ::: "memory");
        __builtin_amdgcn_s_barrier();
    }
}

extern "C" void kernel_launch(void* const* d_in, const int* in_sizes, int n_in,
                              void* d_out, int out_size, void* d_ws, size_t ws_size,
                              hipStream_t stream) {
    const float* img  = (const float*)d_in[0];
    const float* flow = (const float*)d_in[1];
    float* out = (float*)d_out;

    resample2d_kernel<<<NBLK, TPB, 0, stream>>>(img, flow, out);
}